// Round 1
// baseline (743.809 us; speedup 1.0000x reference)
//
#include <hip/hip_runtime.h>
#include <math.h>

#define NITER 18

// ---------------- utility: block reduction over 256 threads ----------------
__device__ __forceinline__ float blockReduceSum256(float v, volatile float* red) {
  #pragma unroll
  for (int o = 32; o; o >>= 1) v += __shfl_down(v, o, 64);
  if ((threadIdx.x & 63) == 0) red[threadIdx.x >> 6] = v;
  __syncthreads();
  if (threadIdx.x == 0) red[4] = red[0] + red[1] + red[2] + red[3];
  __syncthreads();
  return red[4];
}

// ---- gather rows + double-normalize (mirrors reference); z[1024][128], sq[r]=sum z^2
__global__ __launch_bounds__(128) void k_gather_norm(
    const float* __restrict__ x1, const float* __restrict__ x2,
    const int* __restrict__ i1, const int* __restrict__ i2,
    float* __restrict__ z, float* __restrict__ sq) {
  int r = blockIdx.x, t = threadIdx.x;
  const float* src = (r < 512) ? (x1 + (size_t)i1[r] * 128)
                               : (x2 + (size_t)i2[r - 512] * 128);
  float v = src[t];
  __shared__ float red[2];
  // normalize #1 (per z1/z2 row)
  float ss = v * v;
  #pragma unroll
  for (int o = 32; o; o >>= 1) ss += __shfl_down(ss, o, 64);
  if ((t & 63) == 0) red[t >> 6] = ss;
  __syncthreads();
  float n2 = red[0] + red[1];
  v /= fmaxf(sqrtf(n2), 1e-12f);
  __syncthreads();
  // normalize #2 (of the concatenated z)
  ss = v * v;
  #pragma unroll
  for (int o = 32; o; o >>= 1) ss += __shfl_down(ss, o, 64);
  if ((t & 63) == 0) red[t >> 6] = ss;
  __syncthreads();
  n2 = red[0] + red[1];
  v /= fmaxf(sqrtf(n2), 1e-12f);
  __syncthreads();
  // sq = sum(z*z) of final z (used by _rbf)
  ss = v * v;
  #pragma unroll
  for (int o = 32; o; o >>= 1) ss += __shfl_down(ss, o, 64);
  if ((t & 63) == 0) red[t >> 6] = ss;
  __syncthreads();
  if (t == 0) sq[r] = red[0] + red[1];
  z[r * 128 + t] = v;
}

// ---- K = exp(-d2/(2*sigma)) for z[:512] x z[:1024]; also G = 1 + 0.1*I + K[:, :512]
__global__ __launch_bounds__(256) void k_rbf(
    const float* __restrict__ z, const float* __restrict__ sq,
    float* __restrict__ Km, float* __restrict__ G) {
  __shared__ float ZI[32][33];
  __shared__ float ZJ[64][33];
  const float inv2g = 1.0f / 0.14f;  // 1/(2*SIGMA)
  int bi = blockIdx.y * 32;
  int bj = blockIdx.x * 64;
  int t = threadIdx.x;
  int tj = t & 63, ti4 = t >> 6;  // tj: j-local, ti4: 0..3
  float acc[8];
  #pragma unroll
  for (int a = 0; a < 8; ++a) acc[a] = 0.0f;
  for (int kc = 0; kc < 128; kc += 32) {
    for (int l = t; l < 32 * 32; l += 256) { int rr = l >> 5, cc = l & 31; ZI[rr][cc] = z[(bi + rr) * 128 + kc + cc]; }
    for (int l = t; l < 64 * 32; l += 256) { int rr = l >> 5, cc = l & 31; ZJ[rr][cc] = z[(bj + rr) * 128 + kc + cc]; }
    __syncthreads();
    #pragma unroll 8
    for (int kk = 0; kk < 32; ++kk) {
      float bz = ZJ[tj][kk];
      #pragma unroll
      for (int ii = 0; ii < 8; ++ii) acc[ii] += ZI[ti4 + 4 * ii][kk] * bz;
    }
    __syncthreads();
  }
  int j = bj + tj;
  float sj = sq[j];
  #pragma unroll
  for (int ii = 0; ii < 8; ++ii) {
    int i = bi + ti4 + 4 * ii;
    float d2 = sq[i] + sj - 2.0f * acc[ii];
    float kv = expf(-d2 * inv2g);
    Km[i * 1024 + j] = kv;
    if (j < 512) G[i * 512 + j] = kv + 1.0f + ((i == j) ? 0.1f : 0.0f);
  }
}

// ---- CG init: x=0, r = 2*(1 - e_b), z = M^-1 r, p = z, rho = r.z  (rows = systems)
__global__ __launch_bounds__(256) void k_init(
    float* __restrict__ X, float* __restrict__ R, float* __restrict__ P,
    float* __restrict__ rho) {
  __shared__ float red[8];
  int b = blockIdx.x, t = threadIdx.x;
  float rz = 0.0f;
  #pragma unroll
  for (int e = 0; e < 2; ++e) {
    int i = t + e * 256;
    float r = (i == b) ? 0.0f : 2.0f;
    // sum(r) = 1022 exactly; M_n^-1 = (1/1.1)(I - J/(511+1.1))
    float zv = (i == b) ? 0.0f : (r - 1022.0f / 512.1f) * (1.0f / 1.1f);
    X[b * 512 + i] = 0.0f;
    R[b * 512 + i] = r;
    P[b * 512 + i] = zv;
    rz += r * zv;
  }
  float s = blockReduceSum256(rz, red);
  if (t == 0) rho[b] = s;
}

// ---- Q = P * G (512x512x512, f32). G symmetric so (P G)[b,:] == (G p_b)^T.
__global__ __launch_bounds__(256) void k_matmul(
    const float* __restrict__ P, const float* __restrict__ G, float* __restrict__ Q) {
  __shared__ float Pt[16][64];  // [k][m]
  __shared__ float Gt[16][64];  // [k][n]
  int bm = blockIdx.y * 64, bn = blockIdx.x * 64;
  int t = threadIdx.x;
  int tn = t & 15, tm = t >> 4;
  float acc[4][4] = {};
  for (int kc = 0; kc < 512; kc += 16) {
    {
      int m0 = t >> 4, k = t & 15;
      #pragma unroll
      for (int e = 0; e < 4; ++e) Pt[k][m0 + e * 16] = P[(bm + m0 + e * 16) * 512 + kc + k];
    }
    {
      int n = t & 63, k0 = t >> 6;
      #pragma unroll
      for (int e = 0; e < 4; ++e) Gt[k0 + e * 4][n] = G[(kc + k0 + e * 4) * 512 + bn + n];
    }
    __syncthreads();
    #pragma unroll
    for (int kk = 0; kk < 16; ++kk) {
      float4 a = *(const float4*)&Pt[kk][tm * 4];
      float4 bv = *(const float4*)&Gt[kk][tn * 4];
      acc[0][0] += a.x * bv.x; acc[0][1] += a.x * bv.y; acc[0][2] += a.x * bv.z; acc[0][3] += a.x * bv.w;
      acc[1][0] += a.y * bv.x; acc[1][1] += a.y * bv.y; acc[1][2] += a.y * bv.z; acc[1][3] += a.y * bv.w;
      acc[2][0] += a.z * bv.x; acc[2][1] += a.z * bv.y; acc[2][2] += a.z * bv.z; acc[2][3] += a.z * bv.w;
      acc[3][0] += a.w * bv.x; acc[3][1] += a.w * bv.y; acc[3][2] += a.w * bv.z; acc[3][3] += a.w * bv.w;
    }
    __syncthreads();
  }
  #pragma unroll
  for (int i = 0; i < 4; ++i) {
    float4 o = make_float4(acc[i][0], acc[i][1], acc[i][2], acc[i][3]);
    *(float4*)&Q[(bm + tm * 4 + i) * 512 + bn + tn * 4] = o;
  }
}

// ---- one CG update step for system b (row b of all state matrices)
__global__ __launch_bounds__(256) void k_cgupd(
    const float* __restrict__ Km, float* __restrict__ X, float* __restrict__ R,
    float* __restrict__ P, const float* __restrict__ Q, float* __restrict__ rho) {
  __shared__ float red[8];
  int b = blockIdx.x, t = threadIdx.x;
  int i0 = t, i1 = t + 256;
  size_t o0 = (size_t)b * 512 + i0, o1 = (size_t)b * 512 + i1;
  float p0 = P[o0], p1 = P[o1];
  float w0 = (i0 == b) ? 0.0f : Km[b * 1024 + i0];
  float w1 = (i1 == b) ? 0.0f : Km[b * 1024 + i1];
  float sigma = blockReduceSum256(p0 + p1, red);          // 1^T p
  float tau   = blockReduceSum256(w0 * p0 + w1 * p1, red); // w^T p
  // q = G p - w*(1^T p) - (w^T p)*1, masked at b
  float q0 = (i0 == b) ? 0.0f : (Q[o0] - w0 * sigma - tau);
  float q1 = (i1 == b) ? 0.0f : (Q[o1] - w1 * sigma - tau);
  float pq = blockReduceSum256(p0 * q0 + p1 * q1, red);
  float rh = rho[b];
  float alpha = rh / fmaxf(pq, 1e-30f);
  float x0 = X[o0] + alpha * p0, x1v = X[o1] + alpha * p1;
  float r0 = R[o0] - alpha * q0, r1 = R[o1] - alpha * q1;
  float sumr = blockReduceSum256(r0 + r1, red);
  float z0 = (i0 == b) ? 0.0f : (r0 - sumr * (1.0f / 512.1f)) * (1.0f / 1.1f);
  float z1 = (i1 == b) ? 0.0f : (r1 - sumr * (1.0f / 512.1f)) * (1.0f / 1.1f);
  float rznew = blockReduceSum256(r0 * z0 + r1 * z1, red);
  float beta = rznew / fmaxf(rh, 1e-30f);
  P[o0] = z0 + beta * p0; P[o1] = z1 + beta * p1;
  X[o0] = x0; X[o1] = x1v;
  R[o0] = r0; R[o1] = r1;
  if (t == 0) rho[b] = rznew;
}

// ---- per-system loss contribution: sum_i a_i*Ks[i,b] - (sum_i a_i)*Ks[b,b]
__global__ __launch_bounds__(256) void k_loss(
    const float* __restrict__ Km, const float* __restrict__ X,
    double* __restrict__ contrib) {
  __shared__ float red[8];
  int b = blockIdx.x, t = threadIdx.x;
  float pa = 0.0f, pn = 0.0f;
  #pragma unroll
  for (int e = 0; e < 2; ++e) {
    int i = t + e * 256;
    float a = fminf(fmaxf(X[(size_t)b * 512 + i], 0.0f), 1.0f);  // clip(relu(x),0,1)
    pa += a;
    pn += a * Km[(size_t)i * 1024 + 512 + b];  // Ks[i, b]
  }
  float sum_a = blockReduceSum256(pa, red);
  float negs  = blockReduceSum256(pn, red);
  if (t == 0) {
    double c = (double)negs - (double)sum_a * (double)Km[(size_t)b * 1024 + 512 + b];
    contrib[b] = c;
  }
}

__global__ __launch_bounds__(256) void k_finish(const double* __restrict__ contrib,
                                                float* __restrict__ out) {
  int t = threadIdx.x;
  double s = contrib[t] + contrib[t + 256];
  #pragma unroll
  for (int o = 32; o; o >>= 1) s += __shfl_down(s, o, 64);
  __shared__ double red[4];
  if ((t & 63) == 0) red[t >> 6] = s;
  __syncthreads();
  if (t == 0) out[0] = (float)((red[0] + red[1] + red[2] + red[3]) / 512.0);
}

extern "C" void kernel_launch(void* const* d_in, const int* in_sizes, int n_in,
                              void* d_out, int out_size, void* d_ws, size_t ws_size,
                              hipStream_t stream) {
  const float* x1 = (const float*)d_in[0];
  const float* x2 = (const float*)d_in[1];
  const int* i1 = (const int*)d_in[2];
  const int* i2 = (const int*)d_in[3];

  float* ws = (float*)d_ws;
  float* z   = ws;                    // 1024*128
  float* sq  = z + 1024 * 128;        // 1024
  float* Km  = sq + 1024;             // 512*1024
  float* G   = Km + 512 * 1024;       // 512*512
  float* X   = G + 512 * 512;
  float* R   = X + 512 * 512;
  float* P   = R + 512 * 512;
  float* Q   = P + 512 * 512;
  float* rho = Q + 512 * 512;         // 512
  double* contrib = (double*)(rho + 512);  // 512 doubles (16B-aligned offset)

  k_gather_norm<<<1024, 128, 0, stream>>>(x1, x2, i1, i2, z, sq);
  k_rbf<<<dim3(16, 16), 256, 0, stream>>>(z, sq, Km, G);
  k_init<<<512, 256, 0, stream>>>(X, R, P, rho);
  for (int it = 0; it < NITER; ++it) {
    k_matmul<<<dim3(8, 8), 256, 0, stream>>>(P, G, Q);
    k_cgupd<<<512, 256, 0, stream>>>(Km, X, R, P, Q, rho);
  }
  k_loss<<<512, 256, 0, stream>>>(Km, X, contrib);
  k_finish<<<1, 256, 0, stream>>>(contrib, (float*)d_out);
}